// Round 11
// baseline (270.640 us; speedup 1.0000x reference)
//
#include <hip/hip_runtime.h>
#include <math.h>

#define BB 8
#define SS 2048
#define EE 1024
#define HH 64
#define MM (BB * SS)   // 16384 rows

typedef unsigned short u16;
typedef __attribute__((ext_vector_type(8))) short short8;   // 8 x bf16
typedef __attribute__((ext_vector_type(4))) float floatx4;  // mfma C/D

__device__ __forceinline__ u16 f2bf(float f) {
    union { float f; unsigned u; } a; a.f = f;
    unsigned r = a.u + 0x7fffu + ((a.u >> 16) & 1u);   // RNE
    return (u16)(r >> 16);
}

// Split two fp32 into packed bf16 hi (truncated) and bf16 lo (residual, truncated).
// hi+lo reproduces fp32 to ~2^-16 relative.
__device__ __forceinline__ void split2(float f0, float f1, unsigned& hp, unsigned& lp) {
    union { float f; unsigned u; } a0, a1, h0, h1, l0, l1;
    a0.f = f0; a1.f = f1;
    h0.u = a0.u & 0xffff0000u;
    h1.u = a1.u & 0xffff0000u;
    l0.f = f0 - h0.f;
    l1.f = f1 - h1.f;
    hp = __builtin_amdgcn_perm(a1.u, a0.u, 0x07060302u);  // [hi16(f1)|hi16(f0)]
    lp = __builtin_amdgcn_perm(l1.u, l0.u, 0x07060302u);
}

// Async global->LDS, 16B per lane. lds base is wave-uniform; HW adds lane*16.
__device__ __forceinline__ void async_copy16(const u16* g, u16* l) {
    __builtin_amdgcn_global_load_lds(
        (const __attribute__((address_space(1))) unsigned*)g,
        (__attribute__((address_space(3))) unsigned*)l, 16, 0, 0);
}

// ---- DPP 16-lane butterfly reductions (VALU pipe, no LDS traffic) ----------
template <int CTRL>
__device__ __forceinline__ float dppf(float x) {
    union { float f; int i; } a, b;
    a.f = x;
    b.i = __builtin_amdgcn_update_dpp(a.i, a.i, CTRL, 0xF, 0xF, true);
    return b.f;
}
__device__ __forceinline__ float red_max16(float x) {
    x = fmaxf(x, dppf<0xB1>(x));
    x = fmaxf(x, dppf<0x4E>(x));
    x = fmaxf(x, dppf<0x141>(x));
    x = fmaxf(x, dppf<0x140>(x));
    return x;
}
__device__ __forceinline__ float red_sum16(float x) {
    x += dppf<0xB1>(x);
    x += dppf<0x4E>(x);
    x += dppf<0x141>(x);
    x += dppf<0x140>(x);
    return x;
}

// ---------------------------------------------------------------------------
// W pre-pack: fp32 W[1024][64] -> bf16 hi/lo fragments in exact MFMA B-frag
// order. Fragment f = t*8 + ks*4 + nt. Wq pre-scaled by 0.125 (exact pow2).
// ---------------------------------------------------------------------------
#define WP_MAT 131072   // u16 per matrix (128 frags * 2 hl * 512 shorts)

__global__ __launch_bounds__(512) void pack_w(
    const float* __restrict__ W0, const float* __restrict__ W1, const float* __restrict__ W2,
    u16* __restrict__ Wp)
{
    const int which = blockIdx.y;
    const float* __restrict__ W = (which == 0) ? W0 : (which == 1) ? W1 : W2;
    const float scale = (which == 0) ? 0.125f : 1.0f;   // exact pow2
    const int t    = blockIdx.x;           // k-chunk 0..15
    const int tid  = threadIdx.x;          // 0..511
    const int ks   = tid >> 8;
    const int nt   = (tid >> 6) & 3;
    const int lane = tid & 63;
    const int n    = lane & 15;
    const int g    = lane >> 4;

    const int k0 = t * 64 + ks * 32 + g * 8;
    const int c  = nt * 16 + n;

    float e[8];
    #pragma unroll
    for (int j = 0; j < 8; ++j) e[j] = W[(size_t)(k0 + j) * HH + c] * scale;

    unsigned hp[4], lp[4];
    #pragma unroll
    for (int i = 0; i < 4; ++i) split2(e[2 * i], e[2 * i + 1], hp[i], lp[i]);

    u16* dst = Wp + (size_t)which * WP_MAT
                  + ((size_t)(t * 8 + ks * 4 + nt) * 2) * 512 + lane * 8;
    *(uint4*)dst         = (uint4){hp[0], hp[1], hp[2], hp[3]};
    *(uint4*)(dst + 512) = (uint4){lp[0], lp[1], lp[2], lp[3]};
}

// ---------------------------------------------------------------------------
// Projection GEMM via bf16 MFMA + hi/lo compensation (3 passes).
// out[M x 64] = A[M x 1024] @ W[1024 x 64] + b.
// v11: ONE-PAGE-PER-INSTRUCTION A loads. Six schedule variants were flat at
//     81-87us and warm-cache runs identical -> the invariant was the A access
//     pattern: each fragment-layout load touched 16 distinct 4KB pages per
//     instruction (rows are page-sized), saturating address translation at
//     ~1.3 TB/s. Now wave w stages its 16 rows with 16 coalesced dword loads
//     (instr j: lane l reads A[w16+j][t*64+l], 256B contiguous, 1 page) into
//     a wave-private padded LDS tile (stride 66 floats: writes 2-way/free,
//     float2 fragment reads 4-way/1.58x). split2/MFMA/W-path bit-identical.
//     LDS 65.5 KB -> 2 blocks/CU. Flash = R7-best, untouched.
// ---------------------------------------------------------------------------
#define PCH 16   // 64-k chunks

#define STAGE_W(TSTAGE, SBUF)                                                  \
    {                                                                          \
        const u16* src_ = wpb + (size_t)(TSTAGE) * 8192 + wave * 2048 + lane * 8; \
        u16* dst_ = &Wb[SBUF][wave * 2048];                                    \
        async_copy16(src_ + 0 * 512, dst_ + 0 * 512);                          \
        async_copy16(src_ + 1 * 512, dst_ + 1 * 512);                          \
        async_copy16(src_ + 2 * 512, dst_ + 2 * 512);                          \
        async_copy16(src_ + 3 * 512, dst_ + 3 * 512);                          \
    }

// 16 coalesced loads: instr j covers ONE row (256B contiguous, ONE page).
#define LOAD_A_REGS(RA, T)                                                     \
    _Pragma("unroll")                                                          \
    for (int j = 0; j < 16; ++j)                                               \
        RA[j] = apw[(size_t)j * EE + (T) * 64 + lane];

// Wave-private padded store: bank (2j+lane)%32 -> 2-way aliasing (free).
#define WRITE_A_LDS(RA, BUF)                                                   \
    _Pragma("unroll")                                                          \
    for (int j = 0; j < 16; ++j)                                               \
        Alds[BUF][wave][j * 66 + lane] = RA[j];

// One 64-k chunk: stage W(t+1) + load A(t+1) rows coalesced; fragments of
// chunk t from Alds[CUR] (float2 reads), split2 in-reg, 24 MFMA from Wb[CUR];
// write A(t+1) to the other buffer; barrier.
#define PROJ_CHUNK(CUR, TNEXT)                                                     \
    {                                                                              \
        if ((TNEXT) < PCH) {                                                       \
            STAGE_W(TNEXT, (CUR) ^ 1);                                             \
            LOAD_A_REGS(rA, TNEXT);                                                \
        }                                                                          \
        const float* ab = &Alds[CUR][wave][n * 66];                                \
        short8 ah0, ah1, al0, al1;                                                 \
        {                                                                          \
            const float2 e0 = *(const float2*)(ab + g * 8 + 0);                    \
            const float2 e1 = *(const float2*)(ab + g * 8 + 2);                    \
            const float2 e2 = *(const float2*)(ab + g * 8 + 4);                    \
            const float2 e3 = *(const float2*)(ab + g * 8 + 6);                    \
            const float2 f0 = *(const float2*)(ab + 32 + g * 8 + 0);               \
            const float2 f1 = *(const float2*)(ab + 32 + g * 8 + 2);               \
            const float2 f2 = *(const float2*)(ab + 32 + g * 8 + 4);               \
            const float2 f3 = *(const float2*)(ab + 32 + g * 8 + 6);               \
            unsigned hp0, lp0, hp1, lp1, hp2, lp2, hp3, lp3;                       \
            split2(e0.x, e0.y, hp0, lp0);                                          \
            split2(e1.x, e1.y, hp1, lp1);                                          \
            split2(e2.x, e2.y, hp2, lp2);                                          \
            split2(e3.x, e3.y, hp3, lp3);                                          \
            union { uint4 u; short8 s; } ch_, cl_;                                 \
            ch_.u = (uint4){hp0, hp1, hp2, hp3};                                   \
            cl_.u = (uint4){lp0, lp1, lp2, lp3};                                   \
            ah0 = ch_.s; al0 = cl_.s;                                              \
            split2(f0.x, f0.y, hp0, lp0);                                          \
            split2(f1.x, f1.y, hp1, lp1);                                          \
            split2(f2.x, f2.y, hp2, lp2);                                          \
            split2(f3.x, f3.y, hp3, lp3);                                          \
            ch_.u = (uint4){hp0, hp1, hp2, hp3};                                   \
            cl_.u = (uint4){lp0, lp1, lp2, lp3};                                   \
            ah1 = ch_.s; al1 = cl_.s;                                              \
        }                                                                          \
        _Pragma("unroll")                                                          \
        for (int nt = 0; nt < 4; ++nt) {                                           \
            const short8 whf = *(const short8*)&Wb[CUR][nt * 1024 + lane * 8];     \
            const short8 wlf = *(const short8*)&Wb[CUR][nt * 1024 + 512 + lane * 8]; \
            acc[nt] = __builtin_amdgcn_mfma_f32_16x16x32_bf16(ah0, whf, acc[nt], 0, 0, 0); \
            acc[nt] = __builtin_amdgcn_mfma_f32_16x16x32_bf16(al0, whf, acc[nt], 0, 0, 0); \
            acc[nt] = __builtin_amdgcn_mfma_f32_16x16x32_bf16(ah0, wlf, acc[nt], 0, 0, 0); \
        }                                                                          \
        _Pragma("unroll")                                                          \
        for (int nt = 0; nt < 4; ++nt) {                                           \
            const short8 whf = *(const short8*)&Wb[CUR][4096 + nt * 1024 + lane * 8]; \
            const short8 wlf = *(const short8*)&Wb[CUR][4096 + nt * 1024 + 512 + lane * 8]; \
            acc[nt] = __builtin_amdgcn_mfma_f32_16x16x32_bf16(ah1, whf, acc[nt], 0, 0, 0); \
            acc[nt] = __builtin_amdgcn_mfma_f32_16x16x32_bf16(al1, whf, acc[nt], 0, 0, 0); \
            acc[nt] = __builtin_amdgcn_mfma_f32_16x16x32_bf16(ah1, wlf, acc[nt], 0, 0, 0); \
        }                                                                          \
        if ((TNEXT) < PCH) WRITE_A_LDS(rA, (CUR) ^ 1);                             \
        __syncthreads();                                                           \
    }

__global__ __launch_bounds__(256) void proj_mfma(
    const float* __restrict__ A0, const float* __restrict__ A1, const float* __restrict__ A2,
    const u16* __restrict__ Wp,
    const float* __restrict__ b0, const float* __restrict__ b1, const float* __restrict__ b2,
    u16* __restrict__ o0, u16* __restrict__ o1, u16* __restrict__ o2)
{
    const int which = blockIdx.y;
    const float* __restrict__ A    = (which == 0) ? A0 : (which == 1) ? A1 : A2;
    const float* __restrict__ bias = (which == 0) ? b0 : (which == 1) ? b1 : b2;
    u16* __restrict__ out          = (which == 0) ? o0 : (which == 1) ? o1 : o2;
    const float bscale = (which == 0) ? 0.125f : 1.0f;

    __shared__ __align__(16) u16 Wb[2][8192];            // 32 KB  (W hi/lo dbuf)
    __shared__ __align__(16) float Alds[2][4][16 * 66];  // 33 KB  (A fp32 dbuf, pad 66)

    const int tid  = threadIdx.x;
    const int lane = tid & 63;
    const int wave = tid >> 6;
    const int n    = lane & 15;
    const int g    = lane >> 4;
    const int row0 = blockIdx.x * 64;

    // coalesced A source: wave w owns rows [row0 + w*16, +16)
    const float* __restrict__ apw = A + (size_t)(row0 + wave * 16) * EE;
    const u16* __restrict__ wpb = Wp + (size_t)which * WP_MAT;

    floatx4 acc[4];
    #pragma unroll
    for (int nt = 0; nt < 4; ++nt) acc[nt] = (floatx4){0.f, 0.f, 0.f, 0.f};

    float rA[16];

    // ---- prologue: W0 -> Wb[0]; A chunk 0 -> regs -> Alds[0] --------------
    STAGE_W(0, 0);
    LOAD_A_REGS(rA, 0);
    WRITE_A_LDS(rA, 0);
    __syncthreads();

    // ---- main loop: chunk t uses buffers t&1 ------------------------------
    for (int tt = 0; tt < PCH; tt += 2) {
        PROJ_CHUNK(0, tt + 1);
        PROJ_CHUNK(1, tt + 2);
    }

    // ---- epilogue: bias + bf16 store -------------------------------------
    #pragma unroll
    for (int nt = 0; nt < 4; ++nt) {
        const float bv = bias[nt * 16 + n] * bscale;
        #pragma unroll
        for (int r = 0; r < 4; ++r) {
            const int row = row0 + wave * 16 + g * 4 + r;
            out[(size_t)row * HH + nt * 16 + n] = f2bf(acc[nt][r] + bv);
        }
    }
}

// ---------------------------------------------------------------------------
// MFMA flash attention (R7 version — best measured): double-buffered 64-key
// tiles, 4 waves (wq = wave&1, ks = wave>>1), DPP softmax, deferred l-sum,
// setprio around MFMA clusters. qp pre-scaled by 0.125.
// ---------------------------------------------------------------------------
__global__ __launch_bounds__(256) void flash_mfma(
    const u16* __restrict__ qp, const u16* __restrict__ kp,
    const u16* __restrict__ vp, float* __restrict__ out)
{
    __shared__ __align__(16) u16 Ks[2][64 * 64];   // row j: 8 chunks, chunk cs at cs^(j&7)
    __shared__ __align__(16) u16 Vt[2][64 * 64];   // row h: 8 j-chunks, chunk cj at cj^(h&7)
    __shared__ __align__(16) u16 Pw[4][16 * 72];

    const int b    = blockIdx.y;
    const int q0   = blockIdx.x * 32;
    const int tid  = threadIdx.x;
    const int lane = tid & 63;
    const int wave = tid >> 6;
    const int wq   = wave & 1;
    const int ks   = wave >> 1;
    const int n    = lane & 15;
    const int g    = lane >> 4;

    const u16* qrow = qp + ((size_t)b * SS + q0 + wq * 16 + n) * HH;
    const short8 qa0 = *(const short8*)(qrow + g * 8);
    const short8 qa1 = *(const short8*)(qrow + 32 + g * 8);

    floatx4 Oa[4];
    #pragma unroll
    for (int ht = 0; ht < 4; ++ht) Oa[ht] = (floatx4){0.f, 0.f, 0.f, 0.f};
    float m_i[4], l_ln[4];
    #pragma unroll
    for (int r = 0; r < 4; ++r) { m_i[r] = -1e30f; l_ln[r] = 0.f; }

    const u16* kb = kp + (size_t)b * SS * HH;
    const u16* vb = vp + (size_t)b * SS * HH;

    const int jK0 = tid >> 3, jK1 = 32 + (tid >> 3), cs = tid & 7;
    const int jV  = (tid & 15) * 4, hV = (tid >> 4) * 4;

    short8  kr0, kr1;
    ushort4 vr0, vr1, vr2, vr3;

    kr0 = *(const short8*)(kb + (size_t)jK0 * HH + cs * 8);
    kr1 = *(const short8*)(kb + (size_t)jK1 * HH + cs * 8);
    vr0 = *(const ushort4*)(vb + (size_t)(jV + 0) * HH + hV);
    vr1 = *(const ushort4*)(vb + (size_t)(jV + 1) * HH + hV);
    vr2 = *(const ushort4*)(vb + (size_t)(jV + 2) * HH + hV);
    vr3 = *(const ushort4*)(vb + (size_t)(jV + 3) * HH + hV);
    {
        *(short8*)&Ks[0][jK0 * 64 + ((cs ^ (jK0 & 7)) << 3)] = kr0;
        *(short8*)&Ks[0][jK1 * 64 + ((cs ^ (jK1 & 7)) << 3)] = kr1;
        const u16* a0 = (const u16*)&vr0; const u16* a1 = (const u16*)&vr1;
        const u16* a2 = (const u16*)&vr2; const u16* a3 = (const u16*)&vr3;
        #pragma unroll
        for (int i = 0; i < 4; ++i) {
            const int h = hV + i;
            ushort4 w; w.x = a0[i]; w.y = a1[i]; w.z = a2[i]; w.w = a3[i];
            *(ushort4*)((char*)&Vt[0][0] + h * 128 + (((jV >> 3) ^ (h & 7)) << 4) + ((jV & 4) << 1)) = w;
        }
    }
    __syncthreads();

    for (int t = 0; t < SS / 64; ++t) {
        const int cur = t & 1;

        if (t + 1 < SS / 64) {
            const size_t kt = (size_t)(t + 1) * 64;
            kr0 = *(const short8*)(kb + (kt + jK0) * HH + cs * 8);
            kr1 = *(const short8*)(kb + (kt + jK1) * HH + cs * 8);
            vr0 = *(const ushort4*)(vb + (kt + jV + 0) * HH + hV);
            vr1 = *(const ushort4*)(vb + (kt + jV + 1) * HH + hV);
            vr2 = *(const ushort4*)(vb + (kt + jV + 2) * HH + hV);
            vr3 = *(const ushort4*)(vb + (kt + jV + 3) * HH + hV);
        }

        floatx4 S[2];
        #pragma unroll
        for (int nt = 0; nt < 2; ++nt) {
            const int j = ks * 32 + nt * 16 + n;
            const short8 kf0 = *(const short8*)&Ks[cur][j * 64 + (((0 + g) ^ (j & 7)) << 3)];
            const short8 kf1 = *(const short8*)&Ks[cur][j * 64 + (((4 + g) ^ (j & 7)) << 3)];
            floatx4 a = (floatx4){0.f, 0.f, 0.f, 0.f};
            __builtin_amdgcn_s_setprio(1);
            a = __builtin_amdgcn_mfma_f32_16x16x32_bf16(qa0, kf0, a, 0, 0, 0);
            a = __builtin_amdgcn_mfma_f32_16x16x32_bf16(qa1, kf1, a, 0, 0, 0);
            __builtin_amdgcn_s_setprio(0);
            S[nt] = a;
        }

        float mx[4];
        #pragma unroll
        for (int r = 0; r < 4; ++r)
            mx[r] = red_max16(fmaxf(S[0][r], S[1][r]));

        float alpha[4];
        #pragma unroll
        for (int r = 0; r < 4; ++r) {
            const float Mn = fmaxf(m_i[r], mx[r]);
            alpha[r] = __expf(m_i[r] - Mn);
            m_i[r]   = Mn;
        }
        float p[2][4];
        #pragma unroll
        for (int nt = 0; nt < 2; ++nt)
            #pragma unroll
            for (int r = 0; r < 4; ++r)
                p[nt][r] = __expf(S[nt][r] - m_i[r]);
        #pragma unroll
        for (int r = 0; r < 4; ++r)
            l_ln[r] = l_ln[r] * alpha[r] + (p[0][r] + p[1][r]);
        #pragma unroll
        for (int ht = 0; ht < 4; ++ht)
            #pragma unroll
            for (int r = 0; r < 4; ++r) Oa[ht][r] *= alpha[r];

        #pragma unroll
        for (int nt = 0; nt < 2; ++nt)
            #pragma unroll
            for (int r = 0; r < 4; ++r)
                Pw[wave][(g * 4 + r) * 72 + nt * 16 + n] = f2bf(p[nt][r]);
        const short8 pa = *(const short8*)&Pw[wave][n * 72 + g * 8];

        __builtin_amdgcn_s_setprio(1);
        #pragma unroll
        for (int ht = 0; ht < 4; ++ht) {
            const int h = ht * 16 + n;
            const short8 vf = *(const short8*)((const char*)&Vt[cur][0] + h * 128 +
                                               ((((ks << 2) + g) ^ (h & 7)) << 4));
            Oa[ht] = __builtin_amdgcn_mfma_f32_16x16x32_bf16(pa, vf, Oa[ht], 0, 0, 0);
        }
        __builtin_amdgcn_s_setprio(0);

        if (t + 1 < SS / 64) {
            const int nx = cur ^ 1;
            *(short8*)&Ks[nx][jK0 * 64 + ((cs ^ (jK0 & 7)) << 3)] = kr0;
            *(short8*)&Ks[nx][jK1 * 64 + ((cs ^ (jK1 & 7)) << 3)] = kr1;
            const u16* a0 = (const u16*)&vr0; const u16* a1 = (const u16*)&vr1;
            const u16* a2 = (const u16*)&vr2; const u16* a3 = (const u16*)&vr3;
            #pragma unroll
            for (int i = 0; i < 4; ++i) {
                const int h = hV + i;
                ushort4 w; w.x = a0[i]; w.y = a1[i]; w.z = a2[i]; w.w = a3[i];
                *(ushort4*)((char*)&Vt[nx][0] + h * 128 + (((jV >> 3) ^ (h & 7)) << 4) + ((jV & 4) << 1)) = w;
            }
        }
        __syncthreads();
    }

    float l_i[4];
    #pragma unroll
    for (int r = 0; r < 4; ++r) l_i[r] = red_sum16(l_ln[r]);

    float* Cb = (float*)&Ks[0][0];          // [wq][16][68]
    float* Cm = Cb + 2 * 16 * 68;           // [wq][16]
    float* Cl = Cm + 32;
    if (ks == 1) {
        #pragma unroll
        for (int ht = 0; ht < 4; ++ht)
            #pragma unroll
            for (int r = 0; r < 4; ++r)
                Cb[(wq * 16 + g * 4 + r) * 68 + ht * 16 + n] = Oa[ht][r];
        if (n == 0)
            #pragma unroll
            for (int r = 0; r < 4; ++r) {
                Cm[wq * 16 + g * 4 + r] = m_i[r];
                Cl[wq * 16 + g * 4 + r] = l_i[r];
            }
    }
    __syncthreads();
    if (ks == 0) {
        float a0v[4], a1v[4], linv[4];
        #pragma unroll
        for (int r = 0; r < 4; ++r) {
            const int m = g * 4 + r;
            const float m1 = Cm[wq * 16 + m], l1 = Cl[wq * 16 + m];
            const float M  = fmaxf(m_i[r], m1);
            const float e0 = __expf(m_i[r] - M), e1 = __expf(m1 - M);
            a0v[r] = e0; a1v[r] = e1;
            linv[r] = 1.f / (l_i[r] * e0 + l1 * e1);
        }
        #pragma unroll
        for (int ht = 0; ht < 4; ++ht)
            #pragma unroll
            for (int r = 0; r < 4; ++r) {
                const float o1 = Cb[(wq * 16 + g * 4 + r) * 68 + ht * 16 + n];
                const float v  = (Oa[ht][r] * a0v[r] + o1 * a1v[r]) * linv[r];
                out[((size_t)b * SS + q0 + wq * 16 + g * 4 + r) * HH + ht * 16 + n] = v;
            }
    }
}

// ---------------------------------------------------------------------------
extern "C" void kernel_launch(void* const* d_in, const int* in_sizes, int n_in,
                              void* d_out, int out_size, void* d_ws, size_t ws_size,
                              hipStream_t stream) {
    const float* query = (const float*)d_in[0];
    const float* key   = (const float*)d_in[1];
    const float* value = (const float*)d_in[2];
    const float* Wq    = (const float*)d_in[3];
    const float* bq    = (const float*)d_in[4];
    const float* Wk    = (const float*)d_in[5];
    const float* bk    = (const float*)d_in[6];
    const float* Wv    = (const float*)d_in[7];
    const float* bv    = (const float*)d_in[8];
    float* out = (float*)d_out;

    u16* qp = (u16*)d_ws;                        // 16384 x 64 bf16 each
    u16* kp = qp + (size_t)MM * HH;
    u16* vp = kp + (size_t)MM * HH;
    u16* Wp = vp + (size_t)MM * HH;              // 3 * 256 KB packed W frags

    dim3 wgrid(EE / 64, 3);
    pack_w<<<wgrid, 512, 0, stream>>>(Wq, Wk, Wv, Wp);

    dim3 pgrid(MM / 64, 3);
    proj_mfma<<<pgrid, 256, 0, stream>>>(query, key, value,
                                         Wp,
                                         bq, bk, bv,
                                         qp, kp, vp);

    dim3 agrid(SS / 32, BB);
    flash_mfma<<<agrid, 256, 0, stream>>>(qp, kp, vp, out);
}

// Round 12
// 257.861 us; speedup vs baseline: 1.0496x; 1.0496x over previous
//
#include <hip/hip_runtime.h>
#include <math.h>

#define BB 8
#define SS 2048
#define EE 1024
#define HH 64
#define MM (BB * SS)   // 16384 rows

typedef unsigned short u16;
typedef __attribute__((ext_vector_type(8))) short short8;   // 8 x bf16
typedef __attribute__((ext_vector_type(4))) float floatx4;  // mfma C/D

__device__ __forceinline__ u16 f2bf(float f) {
    union { float f; unsigned u; } a; a.f = f;
    unsigned r = a.u + 0x7fffu + ((a.u >> 16) & 1u);   // RNE
    return (u16)(r >> 16);
}

// Split two fp32 into packed bf16 hi (truncated) and bf16 lo (residual, truncated).
// hi+lo reproduces fp32 to ~2^-16 relative.
__device__ __forceinline__ void split2(float f0, float f1, unsigned& hp, unsigned& lp) {
    union { float f; unsigned u; } a0, a1, h0, h1, l0, l1;
    a0.f = f0; a1.f = f1;
    h0.u = a0.u & 0xffff0000u;
    h1.u = a1.u & 0xffff0000u;
    l0.f = f0 - h0.f;
    l1.f = f1 - h1.f;
    hp = __builtin_amdgcn_perm(a1.u, a0.u, 0x07060302u);  // [hi16(f1)|hi16(f0)]
    lp = __builtin_amdgcn_perm(l1.u, l0.u, 0x07060302u);
}

// Async global->LDS, 16B per lane. lds base is wave-uniform; HW adds lane*16.
__device__ __forceinline__ void async_copy16(const u16* g, u16* l) {
    __builtin_amdgcn_global_load_lds(
        (const __attribute__((address_space(1))) unsigned*)g,
        (__attribute__((address_space(3))) unsigned*)l, 16, 0, 0);
}

// ---- DPP 16-lane butterfly reductions (VALU pipe, no LDS traffic) ----------
template <int CTRL>
__device__ __forceinline__ float dppf(float x) {
    union { float f; int i; } a, b;
    a.f = x;
    b.i = __builtin_amdgcn_update_dpp(a.i, a.i, CTRL, 0xF, 0xF, true);
    return b.f;
}
__device__ __forceinline__ float red_max16(float x) {
    x = fmaxf(x, dppf<0xB1>(x));
    x = fmaxf(x, dppf<0x4E>(x));
    x = fmaxf(x, dppf<0x141>(x));
    x = fmaxf(x, dppf<0x140>(x));
    return x;
}
__device__ __forceinline__ float red_sum16(float x) {
    x += dppf<0xB1>(x);
    x += dppf<0x4E>(x);
    x += dppf<0x141>(x);
    x += dppf<0x140>(x);
    return x;
}

// ---------------------------------------------------------------------------
// W pre-pack: fp32 W[1024][64] -> bf16 hi/lo fragments in exact MFMA B-frag
// order. Fragment f = t*8 + ks*4 + nt. Wq pre-scaled by 0.125 (exact pow2).
// ---------------------------------------------------------------------------
#define WP_MAT 131072   // u16 per matrix (128 frags * 2 hl * 512 shorts)

__global__ __launch_bounds__(512) void pack_w(
    const float* __restrict__ W0, const float* __restrict__ W1, const float* __restrict__ W2,
    u16* __restrict__ Wp)
{
    const int which = blockIdx.y;
    const float* __restrict__ W = (which == 0) ? W0 : (which == 1) ? W1 : W2;
    const float scale = (which == 0) ? 0.125f : 1.0f;   // exact pow2
    const int t    = blockIdx.x;           // k-chunk 0..15
    const int tid  = threadIdx.x;          // 0..511
    const int ks   = tid >> 8;
    const int nt   = (tid >> 6) & 3;
    const int lane = tid & 63;
    const int n    = lane & 15;
    const int g    = lane >> 4;

    const int k0 = t * 64 + ks * 32 + g * 8;
    const int c  = nt * 16 + n;

    float e[8];
    #pragma unroll
    for (int j = 0; j < 8; ++j) e[j] = W[(size_t)(k0 + j) * HH + c] * scale;

    unsigned hp[4], lp[4];
    #pragma unroll
    for (int i = 0; i < 4; ++i) split2(e[2 * i], e[2 * i + 1], hp[i], lp[i]);

    u16* dst = Wp + (size_t)which * WP_MAT
                  + ((size_t)(t * 8 + ks * 4 + nt) * 2) * 512 + lane * 8;
    *(uint4*)dst         = (uint4){hp[0], hp[1], hp[2], hp[3]};
    *(uint4*)(dst + 512) = (uint4){lp[0], lp[1], lp[2], lp[3]};
}

// ---------------------------------------------------------------------------
// Projection GEMM via bf16 MFMA + hi/lo compensation (3 passes).
// out[M x 64] = A[M x 1024] @ W[1024 x 64] + b.
// v9: DEPTH-2 STAGE PIPELINE (best-measured variant, locked in). 3 W buffers
//     + 3 A slots; chunk t stages W(t+2) and prefetches A(t+3); barrier waits
//     vmcnt(12) -> only S(t+1) (issued 2 chunks earlier) must be done. 4
//     waves, 256 thr. LDS 48 KB -> 3 blocks/CU. Indices literal (rule #20).
// ---------------------------------------------------------------------------
#define PCH 16   // 64-k chunks

#define LOAD_A(AV, T)                                   \
    {                                                   \
        const float* p_ = ap + (T) * 64;                \
        AV[0] = *(const float4*)(p_ + 0);               \
        AV[1] = *(const float4*)(p_ + 4);               \
        AV[2] = *(const float4*)(p_ + 32);              \
        AV[3] = *(const float4*)(p_ + 36);              \
    }

#define STAGE_W(TSTAGE, SBUF)                                                  \
    {                                                                          \
        const u16* src_ = wpb + (size_t)(TSTAGE) * 8192 + wave * 2048 + lane * 8; \
        u16* dst_ = &Wb[SBUF][wave * 2048];                                    \
        async_copy16(src_ + 0 * 512, dst_ + 0 * 512);                          \
        async_copy16(src_ + 1 * 512, dst_ + 1 * 512);                          \
        async_copy16(src_ + 2 * 512, dst_ + 2 * 512);                          \
        async_copy16(src_ + 3 * 512, dst_ + 3 * 512);                          \
    }

// Counted barrier: allow N newest vmem ops to stay in flight.
#define VBARN(N)                                                    \
    {                                                               \
        __builtin_amdgcn_sched_barrier(0);                          \
        asm volatile("s_waitcnt vmcnt(" #N ")" ::: "memory");       \
        __builtin_amdgcn_s_barrier();                               \
        __builtin_amdgcn_sched_barrier(0);                          \
    }

// One 64-k chunk (no trailing barrier): stage W chunk TSTAGE into Wb[SBUF]
// (issue order pinned first), split AV in regs, prefetch A chunk TPREF into
// the freed AV, MFMA from Wb[WBUF].
#define PROJ_CHUNK(AV, WBUF, SBUF, TSTAGE, TPREF)                                  \
    {                                                                              \
        if ((TSTAGE) < PCH) STAGE_W(TSTAGE, SBUF);                                 \
        __builtin_amdgcn_sched_barrier(0);                                         \
        short8 ah0, ah1, al0, al1;                                                 \
        {                                                                          \
            unsigned hp0, lp0, hp1, lp1, hp2, lp2, hp3, lp3;                       \
            split2(AV[0].x, AV[0].y, hp0, lp0);                                    \
            split2(AV[0].z, AV[0].w, hp1, lp1);                                    \
            split2(AV[1].x, AV[1].y, hp2, lp2);                                    \
            split2(AV[1].z, AV[1].w, hp3, lp3);                                    \
            union { uint4 u; short8 s; } ch_, cl_;                                 \
            ch_.u = (uint4){hp0, hp1, hp2, hp3};                                   \
            cl_.u = (uint4){lp0, lp1, lp2, lp3};                                   \
            ah0 = ch_.s; al0 = cl_.s;                                              \
            split2(AV[2].x, AV[2].y, hp0, lp0);                                    \
            split2(AV[2].z, AV[2].w, hp1, lp1);                                    \
            split2(AV[3].x, AV[3].y, hp2, lp2);                                    \
            split2(AV[3].z, AV[3].w, hp3, lp3);                                    \
            ch_.u = (uint4){hp0, hp1, hp2, hp3};                                   \
            cl_.u = (uint4){lp0, lp1, lp2, lp3};                                   \
            ah1 = ch_.s; al1 = cl_.s;                                              \
        }                                                                          \
        if ((TPREF) < PCH) LOAD_A(AV, TPREF);                                      \
        _Pragma("unroll")                                                          \
        for (int nt = 0; nt < 4; ++nt) {                                           \
            const short8 whf = *(const short8*)&Wb[WBUF][nt * 1024 + lane * 8];    \
            const short8 wlf = *(const short8*)&Wb[WBUF][nt * 1024 + 512 + lane * 8]; \
            acc[nt] = __builtin_amdgcn_mfma_f32_16x16x32_bf16(ah0, whf, acc[nt], 0, 0, 0); \
            acc[nt] = __builtin_amdgcn_mfma_f32_16x16x32_bf16(al0, whf, acc[nt], 0, 0, 0); \
            acc[nt] = __builtin_amdgcn_mfma_f32_16x16x32_bf16(ah0, wlf, acc[nt], 0, 0, 0); \
        }                                                                          \
        _Pragma("unroll")                                                          \
        for (int nt = 0; nt < 4; ++nt) {                                           \
            const short8 whf = *(const short8*)&Wb[WBUF][4096 + nt * 1024 + lane * 8]; \
            const short8 wlf = *(const short8*)&Wb[WBUF][4096 + nt * 1024 + 512 + lane * 8]; \
            acc[nt] = __builtin_amdgcn_mfma_f32_16x16x32_bf16(ah1, whf, acc[nt], 0, 0, 0); \
            acc[nt] = __builtin_amdgcn_mfma_f32_16x16x32_bf16(al1, whf, acc[nt], 0, 0, 0); \
            acc[nt] = __builtin_amdgcn_mfma_f32_16x16x32_bf16(ah1, wlf, acc[nt], 0, 0, 0); \
        }                                                                          \
    }

__global__ __launch_bounds__(256) void proj_mfma(
    const float* __restrict__ A0, const float* __restrict__ A1, const float* __restrict__ A2,
    const u16* __restrict__ Wp,
    const float* __restrict__ b0, const float* __restrict__ b1, const float* __restrict__ b2,
    u16* __restrict__ o0, u16* __restrict__ o1, u16* __restrict__ o2)
{
    const int which = blockIdx.y;
    const float* __restrict__ A    = (which == 0) ? A0 : (which == 1) ? A1 : A2;
    const float* __restrict__ bias = (which == 0) ? b0 : (which == 1) ? b1 : b2;
    u16* __restrict__ out          = (which == 0) ? o0 : (which == 1) ? o1 : o2;
    const float bscale = (which == 0) ? 0.125f : 1.0f;

    __shared__ __align__(16) u16 Wb[3][8192];   // 48 KB: triple buffer

    const int tid  = threadIdx.x;
    const int lane = tid & 63;
    const int wave = tid >> 6;
    const int n    = lane & 15;
    const int g    = lane >> 4;
    const int row0 = blockIdx.x * 64;

    // A fragment source: row (row0 + wave*16 + n), 8 contiguous floats at g*8
    const float* __restrict__ ap = A + (size_t)(row0 + wave * 16 + n) * EE + g * 8;
    const u16* __restrict__ wpb = Wp + (size_t)which * WP_MAT;

    floatx4 acc[4];
    #pragma unroll
    for (int nt = 0; nt < 4; ++nt) acc[nt] = (floatx4){0.f, 0.f, 0.f, 0.f};

    // ---- prologue: S0 -> buf0 ; A0,A1,A2 -> slots ; S1 -> buf1 ------------
    // Issue order pinned: S0(4) | A0 A1 A2 (12) | S1(4)  => 20 outstanding.
    float4 avA[4], avB[4], avC[4];
    STAGE_W(0, 0);
    __builtin_amdgcn_sched_barrier(0);
    LOAD_A(avA, 0);
    LOAD_A(avB, 1);
    LOAD_A(avC, 2);
    __builtin_amdgcn_sched_barrier(0);
    STAGE_W(1, 1);
    VBARN(12);   // oldest 8 = S0 + A0 done; A1,A2,S1 in flight

    // ---- t=0: stage S2->buf2, pref A3->avA, compute buf0 ------------------
    PROJ_CHUNK(avA, 0, 2, 2, 3);
    VBARN(8);    // forces A1..S1 done (S1 needed next); S2+A3 in flight

    // ---- steady state t=1..12 (period 3), vmcnt(12) = 2-chunk stage slack --
    for (int tt = 1; tt <= 10; tt += 3) {
        PROJ_CHUNK(avB, 1, 0, tt + 2, tt + 3);  VBARN(12);  // t=tt
        PROJ_CHUNK(avC, 2, 1, tt + 3, tt + 4);  VBARN(12);  // t=tt+1
        PROJ_CHUNK(avA, 0, 2, tt + 4, tt + 5);  VBARN(12);  // t=tt+2
    }
    // after loop: chunks 0..12 done; in flight: S14(buf2), A15.

    // ---- tail: t=13,14,15 --------------------------------------------------
    PROJ_CHUNK(avB, 1, 0, 15, 16);   // stage S15->buf0
    VBARN(8);                        // forces S14 done; A15+S15 in flight
    PROJ_CHUNK(avC, 2, 0, 16, 17);   // compute buf2 (no stage/pref)
    VBARN(0);                        // drain A15 + S15
    PROJ_CHUNK(avA, 0, 0, 16, 17);   // compute buf0 (chunk 15), no barrier

    // ---- epilogue: bias + bf16 store -------------------------------------
    #pragma unroll
    for (int nt = 0; nt < 4; ++nt) {
        const float bv = bias[nt * 16 + n] * bscale;
        #pragma unroll
        for (int r = 0; r < 4; ++r) {
            const int row = row0 + wave * 16 + g * 4 + r;
            out[(size_t)row * HH + nt * 16 + n] = f2bf(acc[nt][r] + bv);
        }
    }
}

// ---------------------------------------------------------------------------
// MFMA flash attention (R7 version — best measured): double-buffered 64-key
// tiles, 4 waves (wq = wave&1, ks = wave>>1), DPP softmax, deferred l-sum,
// setprio around MFMA clusters. qp pre-scaled by 0.125.
// ---------------------------------------------------------------------------
__global__ __launch_bounds__(256) void flash_mfma(
    const u16* __restrict__ qp, const u16* __restrict__ kp,
    const u16* __restrict__ vp, float* __restrict__ out)
{
    __shared__ __align__(16) u16 Ks[2][64 * 64];   // row j: 8 chunks, chunk cs at cs^(j&7)
    __shared__ __align__(16) u16 Vt[2][64 * 64];   // row h: 8 j-chunks, chunk cj at cj^(h&7)
    __shared__ __align__(16) u16 Pw[4][16 * 72];

    const int b    = blockIdx.y;
    const int q0   = blockIdx.x * 32;
    const int tid  = threadIdx.x;
    const int lane = tid & 63;
    const int wave = tid >> 6;
    const int wq   = wave & 1;
    const int ks   = wave >> 1;
    const int n    = lane & 15;
    const int g    = lane >> 4;

    const u16* qrow = qp + ((size_t)b * SS + q0 + wq * 16 + n) * HH;
    const short8 qa0 = *(const short8*)(qrow + g * 8);
    const short8 qa1 = *(const short8*)(qrow + 32 + g * 8);

    floatx4 Oa[4];
    #pragma unroll
    for (int ht = 0; ht < 4; ++ht) Oa[ht] = (floatx4){0.f, 0.f, 0.f, 0.f};
    float m_i[4], l_ln[4];
    #pragma unroll
    for (int r = 0; r < 4; ++r) { m_i[r] = -1e30f; l_ln[r] = 0.f; }

    const u16* kb = kp + (size_t)b * SS * HH;
    const u16* vb = vp + (size_t)b * SS * HH;

    const int jK0 = tid >> 3, jK1 = 32 + (tid >> 3), cs = tid & 7;
    const int jV  = (tid & 15) * 4, hV = (tid >> 4) * 4;

    short8  kr0, kr1;
    ushort4 vr0, vr1, vr2, vr3;

    kr0 = *(const short8*)(kb + (size_t)jK0 * HH + cs * 8);
    kr1 = *(const short8*)(kb + (size_t)jK1 * HH + cs * 8);
    vr0 = *(const ushort4*)(vb + (size_t)(jV + 0) * HH + hV);
    vr1 = *(const ushort4*)(vb + (size_t)(jV + 1) * HH + hV);
    vr2 = *(const ushort4*)(vb + (size_t)(jV + 2) * HH + hV);
    vr3 = *(const ushort4*)(vb + (size_t)(jV + 3) * HH + hV);
    {
        *(short8*)&Ks[0][jK0 * 64 + ((cs ^ (jK0 & 7)) << 3)] = kr0;
        *(short8*)&Ks[0][jK1 * 64 + ((cs ^ (jK1 & 7)) << 3)] = kr1;
        const u16* a0 = (const u16*)&vr0; const u16* a1 = (const u16*)&vr1;
        const u16* a2 = (const u16*)&vr2; const u16* a3 = (const u16*)&vr3;
        #pragma unroll
        for (int i = 0; i < 4; ++i) {
            const int h = hV + i;
            ushort4 w; w.x = a0[i]; w.y = a1[i]; w.z = a2[i]; w.w = a3[i];
            *(ushort4*)((char*)&Vt[0][0] + h * 128 + (((jV >> 3) ^ (h & 7)) << 4) + ((jV & 4) << 1)) = w;
        }
    }
    __syncthreads();

    for (int t = 0; t < SS / 64; ++t) {
        const int cur = t & 1;

        if (t + 1 < SS / 64) {
            const size_t kt = (size_t)(t + 1) * 64;
            kr0 = *(const short8*)(kb + (kt + jK0) * HH + cs * 8);
            kr1 = *(const short8*)(kb + (kt + jK1) * HH + cs * 8);
            vr0 = *(const ushort4*)(vb + (kt + jV + 0) * HH + hV);
            vr1 = *(const ushort4*)(vb + (kt + jV + 1) * HH + hV);
            vr2 = *(const ushort4*)(vb + (kt + jV + 2) * HH + hV);
            vr3 = *(const ushort4*)(vb + (kt + jV + 3) * HH + hV);
        }

        floatx4 S[2];
        #pragma unroll
        for (int nt = 0; nt < 2; ++nt) {
            const int j = ks * 32 + nt * 16 + n;
            const short8 kf0 = *(const short8*)&Ks[cur][j * 64 + (((0 + g) ^ (j & 7)) << 3)];
            const short8 kf1 = *(const short8*)&Ks[cur][j * 64 + (((4 + g) ^ (j & 7)) << 3)];
            floatx4 a = (floatx4){0.f, 0.f, 0.f, 0.f};
            __builtin_amdgcn_s_setprio(1);
            a = __builtin_amdgcn_mfma_f32_16x16x32_bf16(qa0, kf0, a, 0, 0, 0);
            a = __builtin_amdgcn_mfma_f32_16x16x32_bf16(qa1, kf1, a, 0, 0, 0);
            __builtin_amdgcn_s_setprio(0);
            S[nt] = a;
        }

        float mx[4];
        #pragma unroll
        for (int r = 0; r < 4; ++r)
            mx[r] = red_max16(fmaxf(S[0][r], S[1][r]));

        float alpha[4];
        #pragma unroll
        for (int r = 0; r < 4; ++r) {
            const float Mn = fmaxf(m_i[r], mx[r]);
            alpha[r] = __expf(m_i[r] - Mn);
            m_i[r]   = Mn;
        }
        float p[2][4];
        #pragma unroll
        for (int nt = 0; nt < 2; ++nt)
            #pragma unroll
            for (int r = 0; r < 4; ++r)
                p[nt][r] = __expf(S[nt][r] - m_i[r]);
        #pragma unroll
        for (int r = 0; r < 4; ++r)
            l_ln[r] = l_ln[r] * alpha[r] + (p[0][r] + p[1][r]);
        #pragma unroll
        for (int ht = 0; ht < 4; ++ht)
            #pragma unroll
            for (int r = 0; r < 4; ++r) Oa[ht][r] *= alpha[r];

        #pragma unroll
        for (int nt = 0; nt < 2; ++nt)
            #pragma unroll
            for (int r = 0; r < 4; ++r)
                Pw[wave][(g * 4 + r) * 72 + nt * 16 + n] = f2bf(p[nt][r]);
        const short8 pa = *(const short8*)&Pw[wave][n * 72 + g * 8];

        __builtin_amdgcn_s_setprio(1);
        #pragma unroll
        for (int ht = 0; ht < 4; ++ht) {
            const int h = ht * 16 + n;
            const short8 vf = *(const short8*)((const char*)&Vt[cur][0] + h * 128 +
                                               ((((ks << 2) + g) ^ (h & 7)) << 4));
            Oa[ht] = __builtin_amdgcn_mfma_f32_16x16x32_bf16(pa, vf, Oa[ht], 0, 0, 0);
        }
        __builtin_amdgcn_s_setprio(0);

        if (t + 1 < SS / 64) {
            const int nx = cur ^ 1;
            *(short8*)&Ks[nx][jK0 * 64 + ((cs ^ (jK0 & 7)) << 3)] = kr0;
            *(short8*)&Ks[nx][jK1 * 64 + ((cs ^ (jK1 & 7)) << 3)] = kr1;
            const u16* a0 = (const u16*)&vr0; const u16* a1 = (const u16*)&vr1;
            const u16* a2 = (const u16*)&vr2; const u16* a3 = (const u16*)&vr3;
            #pragma unroll
            for (int i = 0; i < 4; ++i) {
                const int h = hV + i;
                ushort4 w; w.x = a0[i]; w.y = a1[i]; w.z = a2[i]; w.w = a3[i];
                *(ushort4*)((char*)&Vt[nx][0] + h * 128 + (((jV >> 3) ^ (h & 7)) << 4) + ((jV & 4) << 1)) = w;
            }
        }
        __syncthreads();
    }

    float l_i[4];
    #pragma unroll
    for (int r = 0; r < 4; ++r) l_i[r] = red_sum16(l_ln[r]);

    float* Cb = (float*)&Ks[0][0];          // [wq][16][68]
    float* Cm = Cb + 2 * 16 * 68;           // [wq][16]
    float* Cl = Cm + 32;
    if (ks == 1) {
        #pragma unroll
        for (int ht = 0; ht < 4; ++ht)
            #pragma unroll
            for (int r = 0; r < 4; ++r)
                Cb[(wq * 16 + g * 4 + r) * 68 + ht * 16 + n] = Oa[ht][r];
        if (n == 0)
            #pragma unroll
            for (int r = 0; r < 4; ++r) {
                Cm[wq * 16 + g * 4 + r] = m_i[r];
                Cl[wq * 16 + g * 4 + r] = l_i[r];
            }
    }
    __syncthreads();
    if (ks == 0) {
        float a0v[4], a1v[4], linv[4];
        #pragma unroll
        for (int r = 0; r < 4; ++r) {
            const int m = g * 4 + r;
            const float m1 = Cm[wq * 16 + m], l1 = Cl[wq * 16 + m];
            const float M  = fmaxf(m_i[r], m1);
            const float e0 = __expf(m_i[r] - M), e1 = __expf(m1 - M);
            a0v[r] = e0; a1v[r] = e1;
            linv[r] = 1.f / (l_i[r] * e0 + l1 * e1);
        }
        #pragma unroll
        for (int ht = 0; ht < 4; ++ht)
            #pragma unroll
            for (int r = 0; r < 4; ++r) {
                const float o1 = Cb[(wq * 16 + g * 4 + r) * 68 + ht * 16 + n];
                const float v  = (Oa[ht][r] * a0v[r] + o1 * a1v[r]) * linv[r];
                out[((size_t)b * SS + q0 + wq * 16 + g * 4 + r) * HH + ht * 16 + n] = v;
            }
    }
}

// ---------------------------------------------------------------------------
extern "C" void kernel_launch(void* const* d_in, const int* in_sizes, int n_in,
                              void* d_out, int out_size, void* d_ws, size_t ws_size,
                              hipStream_t stream) {
    const float* query = (const float*)d_in[0];
    const float* key   = (const float*)d_in[1];
    const float* value = (const float*)d_in[2];
    const float* Wq    = (const float*)d_in[3];
    const float* bq    = (const float*)d_in[4];
    const float* Wk    = (const float*)d_in[5];
    const float* bk    = (const float*)d_in[6];
    const float* Wv    = (const float*)d_in[7];
    const float* bv    = (const float*)d_in[8];
    float* out = (float*)d_out;

    u16* qp = (u16*)d_ws;                        // 16384 x 64 bf16 each
    u16* kp = qp + (size_t)MM * HH;
    u16* vp = kp + (size_t)MM * HH;
    u16* Wp = vp + (size_t)MM * HH;              // 3 * 256 KB packed W frags

    dim3 wgrid(EE / 64, 3);
    pack_w<<<wgrid, 512, 0, stream>>>(Wq, Wk, Wv, Wp);

    dim3 pgrid(MM / 64, 3);
    proj_mfma<<<pgrid, 256, 0, stream>>>(query, key, value,
                                         Wp,
                                         bq, bk, bv,
                                         qp, kp, vp);

    dim3 agrid(SS / 32, BB);
    flash_mfma<<<agrid, 256, 0, stream>>>(qp, kp, vp, out);
}